// Round 8
// baseline (1329.118 us; speedup 1.0000x reference)
//
#include <hip/hip_runtime.h>
#include <hip/hip_bf16.h>
#include <math.h>

// InternImage DCNv3 block forward — CORRECTNESS BUILD, fp32 in / fp32 OUT.
// World (established r0-r7): all 27 inputs fp32 (sizes+stats verified on device),
// OUTPUT IS FLOAT32 (reference returns float32; "(bf16...)" in the test label is
// a hardcoded fstring).  r3/r4/r5's absmax-13.09 was my bf16 output being read
// as fp32 pairs.  This round = r5 naive forward, final store as float.
// ws (fp32): F0..F3 = N*192 each | Fm = N*96 | Fc = N*12  -> 44 MB.

#define BATCH 4
#define HH 56
#define WW 56
#define CC 192
#define NPIX (BATCH * HH * WW)   // 12544

__device__ __forceinline__ float gelu_exact(float x) {
    return 0.5f * x * (1.f + erff(x * 0.70710678118654752f));
}

// ---- LN over C=192 (optionally + exact GELU).  One block per pixel, 192 thr.
__global__ void ln_naive(const float* __restrict__ X, const float* __restrict__ w,
                         const float* __restrict__ b, float* __restrict__ out,
                         float eps, int doGelu) {
    const int pix = blockIdx.x;
    const int c   = threadIdx.x;
    __shared__ float buf[CC];
    buf[c] = X[(size_t)pix * CC + c];
    __syncthreads();
    float s = 0.f, q = 0.f;
    for (int k = 0; k < CC; k++) { s += buf[k]; q += buf[k] * buf[k]; }
    const float mu  = s * (1.f / CC);
    const float var = q * (1.f / CC) - mu * mu;
    const float rs  = rsqrtf(var + eps);
    float y = (buf[c] - mu) * rs * w[c] + b[c];
    if (doGelu) y = gelu_exact(y);
    out[(size_t)pix * CC + c] = y;
}

// ---- out = res + LN(D) ----
__global__ void add_ln_naive(const float* __restrict__ res, const float* __restrict__ D,
                             const float* __restrict__ w, const float* __restrict__ b,
                             float* __restrict__ out, float eps) {
    const int pix = blockIdx.x;
    const int c   = threadIdx.x;
    __shared__ float buf[CC];
    buf[c] = D[(size_t)pix * CC + c];
    __syncthreads();
    float s = 0.f, q = 0.f;
    for (int k = 0; k < CC; k++) { s += buf[k]; q += buf[k] * buf[k]; }
    const float mu  = s * (1.f / CC);
    const float var = q * (1.f / CC) - mu * mu;
    const float rs  = rsqrtf(var + eps);
    out[(size_t)pix * CC + c] =
        res[(size_t)pix * CC + c] + (buf[c] - mu) * rs * w[c] + b[c];
}

// ---- naive GEMM: out[n,m] = bias[m] + sum_k A[n,k] * W[k,m] ----
__global__ void gemm_naive(const float* __restrict__ A, const float* __restrict__ W,
                           const float* __restrict__ bias, float* __restrict__ out,
                           int K, int M) {
    const int n = blockIdx.x;
    const int m = blockIdx.y * blockDim.x + threadIdx.x;
    const float* a = A + (size_t)n * K;
    float s = bias[m];
    for (int k = 0; k < K; k++) s += a[k] * W[(size_t)k * M + m];
    out[(size_t)n * M + m] = s;
}

// ---- depthwise 3x3, SAME zero-pad, + bias ----
__global__ void dwconv_naive(const float* __restrict__ xn, const float* __restrict__ dww,
                             const float* __restrict__ dwb, float* __restrict__ outc) {
    const int pix  = blockIdx.x;
    const int c    = threadIdx.x;
    const int bimg = pix / (HH * WW);
    const int hw   = pix % (HH * WW);
    const int h    = hw / WW;
    const int w    = hw % WW;
    float s = dwb[c];
    for (int ky = 0; ky < 3; ky++) {
        const int yy = h + ky - 1;
        if (yy < 0 || yy >= HH) continue;
        for (int kx = 0; kx < 3; kx++) {
            const int xx = w + kx - 1;
            if (xx < 0 || xx >= WW) continue;
            s += xn[((size_t)(bimg * HH + yy) * WW + xx) * CC + c] *
                 dww[(ky * 3 + kx) * CC + c];
        }
    }
    outc[(size_t)pix * CC + c] = s;
}

// ---- softmax over K=8 per (pix, g), in place ----
__global__ void softmax8_naive(float* __restrict__ mask) {
    const int pix = blockIdx.x;
    const int g   = threadIdx.x;          // 12
    float* m = mask + (size_t)pix * 96 + g * 8;
    float mx = m[0];
    for (int k = 1; k < 8; k++) mx = fmaxf(mx, m[k]);
    float e[8]; float se = 0.f;
    for (int k = 0; k < 8; k++) { e[k] = expf(m[k] - mx); se += e[k]; }
    const float inv = 1.f / se;
    for (int k = 0; k < 8; k++) m[k] = e[k] * inv;
}

// ---- cfs[pix,g] = sigmoid(x1[pix,:] . cfs_w[g,:] + cfs_b[g]) ----
__global__ void cfs_naive(const float* __restrict__ x1, const float* __restrict__ cw,
                          const float* __restrict__ cb, float* __restrict__ cfs) {
    const int pix = blockIdx.x;
    const int g   = threadIdx.x;          // 12
    const float* xr = x1 + (size_t)pix * CC;
    float s = cb[g];
    for (int k = 0; k < CC; k++) s += xr[k] * cw[(size_t)g * CC + k];
    cfs[(size_t)pix * 12 + g] = 1.f / (1.f + expf(-s));
}

// ---- deformable bilinear sampling + cfs blend (literal reference reading:
//      component 0 displaces W/column axis, component 1 the H/row axis) ----
__global__ void sample_naive(const float* __restrict__ xp, const float* __restrict__ off,
                             const float* __restrict__ mask, const float* __restrict__ cfs,
                             float* __restrict__ outb) {
    const int pix  = blockIdx.x;
    const int ch   = threadIdx.x;         // 192
    const int g    = ch >> 4;
    const int bimg = pix / (HH * WW);
    const int hw   = pix % (HH * WW);
    const int h    = hw / WW;
    const int w    = hw % WW;
    const int GX[8] = {-1, -1, -1, 0, 0, 1, 1, 1};   // GRID[:,0] -> x (col)
    const int GY[8] = {-1, 0, 1, -1, 1, -1, 0, 1};   // GRID[:,1] -> y (row)
    const size_t imgbase = (size_t)bimg * HH * WW * CC;

    float acc = 0.f;
    for (int k = 0; k < 8; k++) {
        const float px = (float)w + (float)GX[k] + off[(size_t)pix * CC + g * 16 + 2 * k];
        const float py = (float)h + (float)GY[k] + off[(size_t)pix * CC + g * 16 + 2 * k + 1];
        const float fx = floorf(px), fy = floorf(py);
        const float wx = px - fx,  wy = py - fy;
        const int x0 = (int)fx, y0 = (int)fy;
        float v00 = 0.f, v01 = 0.f, v10 = 0.f, v11 = 0.f;
        if (y0 >= 0 && y0 < HH) {
            if (x0 >= 0 && x0 < WW)         v00 = xp[imgbase + (size_t)(y0 * WW + x0) * CC + ch];
            if (x0 + 1 >= 0 && x0 + 1 < WW) v01 = xp[imgbase + (size_t)(y0 * WW + x0 + 1) * CC + ch];
        }
        if (y0 + 1 >= 0 && y0 + 1 < HH) {
            if (x0 >= 0 && x0 < WW)         v10 = xp[imgbase + (size_t)((y0 + 1) * WW + x0) * CC + ch];
            if (x0 + 1 >= 0 && x0 + 1 < WW) v11 = xp[imgbase + (size_t)((y0 + 1) * WW + x0 + 1) * CC + ch];
        }
        const float bil = (1.f - wy) * ((1.f - wx) * v00 + wx * v01)
                        +         wy * ((1.f - wx) * v10 + wx * v11);
        acc += mask[(size_t)pix * 96 + g * 8 + k] * bil;
    }
    const float cf  = cfs[(size_t)pix * 12 + g];
    const float xpc = xp[(size_t)pix * CC + ch];
    outb[(size_t)pix * CC + ch] = acc * (1.f - cf) + xpc * cf;
}

// ---- MLP middle: h2 = gelu(xn2 @ fc1 + b1) @ fc2 + b2.  h1 in LDS. ----
__global__ void mlp_mid_naive(const float* __restrict__ xn2,
                              const float* __restrict__ fc1w, const float* __restrict__ fc1b,
                              const float* __restrict__ fc2w, const float* __restrict__ fc2b,
                              float* __restrict__ h2) {
    const int pix = blockIdx.x;
    const int t   = threadIdx.x;          // 192
    __shared__ float xs[CC];
    __shared__ float h1[768];
    xs[t] = xn2[(size_t)pix * CC + t];
    __syncthreads();
    for (int j = t; j < 768; j += CC) {
        float a = fc1b[j];
        for (int k = 0; k < CC; k++) a += xs[k] * fc1w[(size_t)k * 768 + j];
        h1[j] = gelu_exact(a);
    }
    __syncthreads();
    float a = fc2b[t];
    for (int k = 0; k < 768; k++) a += h1[k] * fc2w[(size_t)k * CC + t];
    h2[(size_t)pix * CC + t] = a;
}

extern "C" void kernel_launch(void* const* d_in, const int* in_sizes, int n_in,
                              void* d_out, int out_size, void* d_ws, size_t ws_size,
                              hipStream_t stream) {
    const float* x      = (const float*)d_in[0];
    const float* n1w    = (const float*)d_in[1];
    const float* n1b    = (const float*)d_in[2];
    const float* n2w    = (const float*)d_in[3];
    const float* n2b    = (const float*)d_in[4];
    const float* rpn1w  = (const float*)d_in[5];
    const float* rpn1b  = (const float*)d_in[6];
    const float* rpn2w  = (const float*)d_in[7];
    const float* rpn2b  = (const float*)d_in[8];
    const float* inpw   = (const float*)d_in[9];
    const float* inpb   = (const float*)d_in[10];
    const float* dww    = (const float*)d_in[11];
    const float* dwb    = (const float*)d_in[12];
    const float* dwlnw  = (const float*)d_in[13];
    const float* dwlnb  = (const float*)d_in[14];
    const float* offw   = (const float*)d_in[15];
    const float* offb   = (const float*)d_in[16];
    const float* maskw  = (const float*)d_in[17];
    const float* maskb  = (const float*)d_in[18];
    const float* cfsw   = (const float*)d_in[19];
    const float* cfsb   = (const float*)d_in[20];
    const float* outpw  = (const float*)d_in[21];
    const float* outpb  = (const float*)d_in[22];
    const float* fc1w   = (const float*)d_in[23];
    const float* fc1b   = (const float*)d_in[24];
    const float* fc2w   = (const float*)d_in[25];
    const float* fc2b   = (const float*)d_in[26];

    const int N = NPIX;                       // 12544
    const size_t NP = (size_t)N * CC;
    float* F0 = (float*)d_ws;                 // xn -> xn2
    float* F1 = F0 + NP;                      // xp -> x2
    float* F2 = F1 + NP;                      // conv -> off -> d -> h2
    float* F3 = F2 + NP;                      // x1 -> blended
    float* Fm = F3 + NP;                      // mask  N*96
    float* Fc = Fm + (size_t)N * 96;          // cfs   N*12

    // 1. xn = LN(x, norm1)
    ln_naive<<<N, CC, 0, stream>>>(x, n1w, n1b, F0, 1e-5f, 0);
    // 2. xp = xn @ in_proj + b
    gemm_naive<<<dim3(N, 1), CC, 0, stream>>>(F0, inpw, inpb, F1, CC, CC);
    // 3. conv = dwconv(xn) + dw_b
    dwconv_naive<<<N, CC, 0, stream>>>(F0, dww, dwb, F2);
    // 4. x1 = gelu(LN(conv, 1e-6))
    ln_naive<<<N, CC, 0, stream>>>(F2, dwlnw, dwlnb, F3, 1e-6f, 1);
    // 5. off = x1 @ off_w + b
    gemm_naive<<<dim3(N, 1), CC, 0, stream>>>(F3, offw, offb, F2, CC, CC);
    // 6. mask logits = x1 @ mask_w + b
    gemm_naive<<<dim3(N, 1), 96, 0, stream>>>(F3, maskw, maskb, Fm, CC, 96);
    // 7. softmax over K=8 (in place)
    softmax8_naive<<<N, 12, 0, stream>>>(Fm);
    // 8. cfs = sigmoid(x1 @ cfs_w^T + b)
    cfs_naive<<<N, 12, 0, stream>>>(F3, cfsw, cfsb, Fc);
    // 9. blended = sample(xp, off, mask, cfs)
    sample_naive<<<N, CC, 0, stream>>>(F1, F2, Fm, Fc, F3);
    // 10. d = blended @ out_proj + b
    gemm_naive<<<dim3(N, 1), CC, 0, stream>>>(F3, outpw, outpb, F2, CC, CC);
    // 11. x2 = x + LN(d, rpn1)
    add_ln_naive<<<N, CC, 0, stream>>>(x, F2, rpn1w, rpn1b, F1, 1e-5f);
    // 12. xn2 = LN(x2, norm2)
    ln_naive<<<N, CC, 0, stream>>>(F1, n2w, n2b, F0, 1e-5f, 0);
    // 13. h2 = gelu(xn2 @ fc1 + b) @ fc2 + b
    mlp_mid_naive<<<N, CC, 0, stream>>>(F0, fc1w, fc1b, fc2w, fc2b, F2);
    // 14. out(FLOAT32) = x2 + LN(h2, rpn2)
    add_ln_naive<<<N, CC, 0, stream>>>(F1, F2, rpn2w, rpn2b, (float*)d_out, 1e-5f);
}

// Round 9
// 506.882 us; speedup vs baseline: 2.6221x; 2.6221x over previous
//
#include <hip/hip_runtime.h>
#include <hip/hip_bf16.h>
#include <math.h>

// InternImage DCNv3 block forward — OPTIMIZED fp32 build (round 9).
// World: 27 fp32 inputs, fp32 output (verified r8, absmax 0.03125).
// This round: tiled/fused fp32 GEMMs (weight reuse), fused sample (softmax+cfs),
// wave-shuffle LNs.  Same math, same fp32 precision as the passing r8 build.
// ws (fp32): F0..F3 = N*192 each | Fm = N*96  -> ~39 MB.

#define BATCH 4
#define HH 56
#define WW 56
#define CC 192
#define NPIX (BATCH * HH * WW)   // 12544

__device__ __forceinline__ float gelu_exact(float x) {
    return 0.5f * x * (1.f + erff(x * 0.70710678118654752f));
}

// ---------------- LN over C=192, one wave per pixel, 4 px/block --------------
__global__ __launch_bounds__(256) void ln4_k(const float* __restrict__ X,
        const float* __restrict__ w, const float* __restrict__ b,
        float* __restrict__ out, float eps)
{
    const int pix  = blockIdx.x * 4 + (threadIdx.x >> 6);
    const int lane = threadIdx.x & 63;
    const size_t base = (size_t)pix * CC;
    float v[3];
    #pragma unroll
    for (int i = 0; i < 3; i++) v[i] = X[base + lane + 64 * i];
    float s = v[0] + v[1] + v[2];
    float q = v[0]*v[0] + v[1]*v[1] + v[2]*v[2];
    #pragma unroll
    for (int off = 32; off > 0; off >>= 1) {
        s += __shfl_xor(s, off, 64);
        q += __shfl_xor(q, off, 64);
    }
    const float mu  = s * (1.f / CC);
    const float var = q * (1.f / CC) - mu * mu;
    const float rs  = rsqrtf(var + eps);
    #pragma unroll
    for (int i = 0; i < 3; i++) {
        const int c = lane + 64 * i;
        out[base + c] = (v[i] - mu) * rs * w[c] + b[c];
    }
}

// ---------------- out = res + LN(D), 4 px/block ------------------------------
__global__ __launch_bounds__(256) void add_ln4_k(const float* __restrict__ res,
        const float* __restrict__ D, const float* __restrict__ w,
        const float* __restrict__ b, float* __restrict__ out, float eps)
{
    const int pix  = blockIdx.x * 4 + (threadIdx.x >> 6);
    const int lane = threadIdx.x & 63;
    const size_t base = (size_t)pix * CC;
    float d[3];
    #pragma unroll
    for (int i = 0; i < 3; i++) d[i] = D[base + lane + 64 * i];
    float s = d[0] + d[1] + d[2];
    float q = d[0]*d[0] + d[1]*d[1] + d[2]*d[2];
    #pragma unroll
    for (int off = 32; off > 0; off >>= 1) {
        s += __shfl_xor(s, off, 64);
        q += __shfl_xor(q, off, 64);
    }
    const float mu  = s * (1.f / CC);
    const float var = q * (1.f / CC) - mu * mu;
    const float rs  = rsqrtf(var + eps);
    #pragma unroll
    for (int i = 0; i < 3; i++) {
        const int c = lane + 64 * i;
        out[base + c] = res[base + c] + (d[i] - mu) * rs * w[c] + b[c];
    }
}

// --------- tiled GEMM: out[N,M] = A[N,192] @ W[192,M] + bias -----------------
// 32 pixels/block, 256 threads.  Thread = (pslot 0..3, cslot 0..63):
// 8 pixels x 3 strided cols {cslot, cslot+64, cslot+128}.  A-tile in LDS,
// wave reads are broadcast (whole wave shares pslot).  M in {192, 96}.
__global__ __launch_bounds__(256) void gemm_k(const float* __restrict__ A,
        const float* __restrict__ W, const float* __restrict__ bias,
        float* __restrict__ out, int M)
{
    __shared__ float As[32][196];    // pad 192->196 keeps rows 16B-aligned
    const int p0    = blockIdx.x * 32;
    const int tid   = threadIdx.x;
    const int pslot = tid >> 6;
    const int cslot = tid & 63;

    for (int idx = tid; idx < 32 * 192; idx += 256) {
        const int r = idx / 192, c = idx - r * 192;
        As[r][c] = A[(size_t)(p0 + r) * 192 + c];
    }
    __syncthreads();

    float acc[8][3];
    #pragma unroll
    for (int j = 0; j < 3; j++) {
        const int m = cslot + 64 * j;
        const float bb = (m < M) ? bias[m] : 0.f;
        #pragma unroll
        for (int p = 0; p < 8; p++) acc[p][j] = bb;
    }

    for (int k = 0; k < 192; k += 4) {
        float wv[4][3];
        #pragma unroll
        for (int kk = 0; kk < 4; kk++)
            #pragma unroll
            for (int j = 0; j < 3; j++) {
                const int m = cslot + 64 * j;
                wv[kk][j] = (m < M) ? W[(size_t)(k + kk) * M + m] : 0.f;
            }
        #pragma unroll
        for (int p = 0; p < 8; p++) {
            const float4 a = *(const float4*)&As[pslot * 8 + p][k];
            #pragma unroll
            for (int j = 0; j < 3; j++)
                acc[p][j] += a.x*wv[0][j] + a.y*wv[1][j] + a.z*wv[2][j] + a.w*wv[3][j];
        }
    }

    #pragma unroll
    for (int j = 0; j < 3; j++) {
        const int m = cslot + 64 * j;
        if (m < M)
            #pragma unroll
            for (int p = 0; p < 8; p++)
                out[(size_t)(p0 + pslot * 8 + p) * M + m] = acc[p][j];
    }
}

// ------- fused depthwise 3x3 conv (SAME) + LN(1e-6) + exact GELU -------------
__global__ __launch_bounds__(192) void dwconv_ln_gelu_k(
        const float* __restrict__ xn, const float* __restrict__ dww,
        const float* __restrict__ dwb, const float* __restrict__ lnw,
        const float* __restrict__ lnb, float* __restrict__ x1)
{
    const int pix  = blockIdx.x;
    const int c    = threadIdx.x;
    const int bimg = pix / (HH * WW);
    const int hw   = pix - bimg * HH * WW;
    const int h    = hw / WW;
    const int w    = hw - h * WW;

    float s = dwb[c];
    #pragma unroll
    for (int ky = 0; ky < 3; ky++) {
        const int yy = h + ky - 1;
        if (yy < 0 || yy >= HH) continue;
        #pragma unroll
        for (int kx = 0; kx < 3; kx++) {
            const int xx = w + kx - 1;
            if (xx < 0 || xx >= WW) continue;
            s += xn[((size_t)(bimg * HH + yy) * WW + xx) * CC + c] *
                 dww[(ky * 3 + kx) * CC + c];
        }
    }
    float sm = s, sq = s * s;
    #pragma unroll
    for (int off = 32; off > 0; off >>= 1) {
        sm += __shfl_xor(sm, off, 64);
        sq += __shfl_xor(sq, off, 64);
    }
    __shared__ float red[6];
    const int wid = threadIdx.x >> 6;
    if ((threadIdx.x & 63) == 0) { red[wid] = sm; red[3 + wid] = sq; }
    __syncthreads();
    const float S = red[0] + red[1] + red[2];
    const float Q = red[3] + red[4] + red[5];
    const float mu  = S * (1.f / CC);
    const float var = Q * (1.f / CC) - mu * mu;
    const float rs  = rsqrtf(var + 1e-6f);
    const float y = (s - mu) * rs * lnw[c] + lnb[c];
    x1[(size_t)pix * CC + c] = gelu_exact(y);
}

// ---- fused sampling: softmax(mask logits) + bilinear gather + cfs blend -----
__global__ __launch_bounds__(192) void sample_k(const float* __restrict__ xp,
        const float* __restrict__ x1g, const float* __restrict__ off,
        const float* __restrict__ mlog, const float* __restrict__ cfsw,
        const float* __restrict__ cfsb, float* __restrict__ outb)
{
    __shared__ float x1s[CC];
    __shared__ float offs[CC];
    __shared__ float mls[96];

    const int pix = blockIdx.x;
    const int t   = threadIdx.x;
    const int bimg = pix / (HH * WW);
    const int hw   = pix - bimg * HH * WW;
    const int h    = hw / WW;
    const int w    = hw - h * WW;

    x1s[t]  = x1g[(size_t)pix * CC + t];
    offs[t] = off[(size_t)pix * CC + t];
    if (t < 96) mls[t] = mlog[(size_t)pix * 96 + t];
    __syncthreads();

    const int g = t >> 4;
    const int c = t & 15;

    // softmax over this group's 8 logits (redundant across 16 lanes — cheap)
    float lg[8];
    float mx = -1e30f;
    #pragma unroll
    for (int k = 0; k < 8; k++) { lg[k] = mls[g * 8 + k]; mx = fmaxf(mx, lg[k]); }
    float se = 0.f;
    #pragma unroll
    for (int k = 0; k < 8; k++) { lg[k] = expf(lg[k] - mx); se += lg[k]; }
    const float inv = 1.f / se;

    const int GX[8] = {-1, -1, -1, 0, 0, 1, 1, 1};   // GRID[:,0] -> x (col)
    const int GY[8] = {-1, 0, 1, -1, 1, -1, 0, 1};   // GRID[:,1] -> y (row)
    const size_t imgbase = (size_t)bimg * HH * WW * CC;

    float acc = 0.f;
    #pragma unroll
    for (int k = 0; k < 8; k++) {
        const float px = (float)w + (float)GX[k] + offs[g * 16 + 2 * k];
        const float py = (float)h + (float)GY[k] + offs[g * 16 + 2 * k + 1];
        const float fx = floorf(px), fy = floorf(py);
        const float wx = px - fx,  wy = py - fy;
        const int x0 = (int)fx, y0 = (int)fy;
        float v00 = 0.f, v01 = 0.f, v10 = 0.f, v11 = 0.f;
        if (y0 >= 0 && y0 < HH) {
            if (x0 >= 0 && x0 < WW)         v00 = xp[imgbase + (size_t)(y0 * WW + x0) * CC + t];
            if (x0 + 1 >= 0 && x0 + 1 < WW) v01 = xp[imgbase + (size_t)(y0 * WW + x0 + 1) * CC + t];
        }
        if (y0 + 1 >= 0 && y0 + 1 < HH) {
            if (x0 >= 0 && x0 < WW)         v10 = xp[imgbase + (size_t)((y0 + 1) * WW + x0) * CC + t];
            if (x0 + 1 >= 0 && x0 + 1 < WW) v11 = xp[imgbase + (size_t)((y0 + 1) * WW + x0 + 1) * CC + t];
        }
        const float bil = (1.f - wy) * ((1.f - wx) * v00 + wx * v01)
                        +         wy * ((1.f - wx) * v10 + wx * v11);
        acc += (lg[k] * inv) * bil;
    }

    // cfs = sigmoid(x1 . cfs_w[g] + cfs_b[g]); dot split across 16 lanes
    float part = 0.f;
    #pragma unroll
    for (int j = 0; j < 12; j++)
        part += x1s[c + 16 * j] * cfsw[(size_t)g * CC + c + 16 * j];
    #pragma unroll
    for (int o = 1; o < 16; o <<= 1) part += __shfl_xor(part, o, 64);
    const float cf = 1.f / (1.f + expf(-(part + cfsb[g])));

    const float xpc = xp[(size_t)pix * CC + t];
    outb[(size_t)pix * CC + t] = acc * (1.f - cf) + xpc * cf;
}

// ---- fused MLP middle: h2 = gelu(xn2 @ fc1 + b1) @ fc2 + b2 -----------------
// 16 pixels/block, 256 threads.  xs (transposed) + h1 (transposed) in LDS (60KB).
#define MT 16
__global__ __launch_bounds__(256) void mlp_k(const float* __restrict__ xn2,
        const float* __restrict__ fc1w, const float* __restrict__ fc1b,
        const float* __restrict__ fc2w, const float* __restrict__ fc2b,
        float* __restrict__ h2)
{
    __shared__ float xs[CC][MT];     // 12 KB  (xs[c][p])
    __shared__ float h1[768][MT];    // 48 KB  (h1[col][p])

    const int p0  = blockIdx.x * MT;
    const int tid = threadIdx.x;

    // stage xn2 transposed; lane-consecutive p => conflict-free LDS writes
    for (int i = tid; i < MT * CC; i += 256) {
        const int p = i & (MT - 1), c = i >> 4;
        xs[c][p] = xn2[(size_t)(p0 + p) * CC + c];
    }
    __syncthreads();

    // ---- fc1 + GELU: cols {tid, tid+256, tid+512}, 16 pixels each ----
    {
        float acc[3][MT];
        #pragma unroll
        for (int j = 0; j < 3; j++) {
            const float bb = fc1b[tid + 256 * j];
            #pragma unroll
            for (int p = 0; p < MT; p++) acc[j][p] = bb;
        }
        for (int k = 0; k < CC; k++) {
            const float w0 = fc1w[(size_t)k * 768 + tid];
            const float w1 = fc1w[(size_t)k * 768 + tid + 256];
            const float w2 = fc1w[(size_t)k * 768 + tid + 512];
            float av[MT];
            #pragma unroll
            for (int q = 0; q < 4; q++) {
                const float4 a = *(const float4*)&xs[k][q * 4];   // broadcast
                av[q*4+0] = a.x; av[q*4+1] = a.y; av[q*4+2] = a.z; av[q*4+3] = a.w;
            }
            #pragma unroll
            for (int p = 0; p < MT; p++) {
                acc[0][p] += av[p] * w0;
                acc[1][p] += av[p] * w1;
                acc[2][p] += av[p] * w2;
            }
        }
        #pragma unroll
        for (int j = 0; j < 3; j++)
            #pragma unroll
            for (int p = 0; p < MT; p++)
                h1[tid + 256 * j][p] = gelu_exact(acc[j][p]);
    }
    __syncthreads();

    // ---- fc2: thread = (pixel-quad tid>>6, col-base tid&63): 4 px x 3 cols ----
    {
        const int c  = tid & 63;
        const int pq = tid >> 6;
        float acc2[3][4];
        #pragma unroll
        for (int j = 0; j < 3; j++) {
            const float bb = fc2b[c + 64 * j];
            #pragma unroll
            for (int p = 0; p < 4; p++) acc2[j][p] = bb;
        }
        for (int k = 0; k < 768; k++) {
            const float4 hv = *(const float4*)&h1[k][pq * 4];     // broadcast x4
            const float w0 = fc2w[(size_t)k * CC + c];
            const float w1 = fc2w[(size_t)k * CC + c + 64];
            const float w2 = fc2w[(size_t)k * CC + c + 128];
            const float hvv[4] = {hv.x, hv.y, hv.z, hv.w};
            #pragma unroll
            for (int p = 0; p < 4; p++) {
                acc2[0][p] += hvv[p] * w0;
                acc2[1][p] += hvv[p] * w1;
                acc2[2][p] += hvv[p] * w2;
            }
        }
        #pragma unroll
        for (int j = 0; j < 3; j++)
            #pragma unroll
            for (int p = 0; p < 4; p++)
                h2[(size_t)(p0 + pq * 4 + p) * CC + c + 64 * j] = acc2[j][p];
    }
}

extern "C" void kernel_launch(void* const* d_in, const int* in_sizes, int n_in,
                              void* d_out, int out_size, void* d_ws, size_t ws_size,
                              hipStream_t stream) {
    const float* x      = (const float*)d_in[0];
    const float* n1w    = (const float*)d_in[1];
    const float* n1b    = (const float*)d_in[2];
    const float* n2w    = (const float*)d_in[3];
    const float* n2b    = (const float*)d_in[4];
    const float* rpn1w  = (const float*)d_in[5];
    const float* rpn1b  = (const float*)d_in[6];
    const float* rpn2w  = (const float*)d_in[7];
    const float* rpn2b  = (const float*)d_in[8];
    const float* inpw   = (const float*)d_in[9];
    const float* inpb   = (const float*)d_in[10];
    const float* dww    = (const float*)d_in[11];
    const float* dwb    = (const float*)d_in[12];
    const float* dwlnw  = (const float*)d_in[13];
    const float* dwlnb  = (const float*)d_in[14];
    const float* offw   = (const float*)d_in[15];
    const float* offb   = (const float*)d_in[16];
    const float* maskw  = (const float*)d_in[17];
    const float* maskb  = (const float*)d_in[18];
    const float* cfsw   = (const float*)d_in[19];
    const float* cfsb   = (const float*)d_in[20];
    const float* outpw  = (const float*)d_in[21];
    const float* outpb  = (const float*)d_in[22];
    const float* fc1w   = (const float*)d_in[23];
    const float* fc1b   = (const float*)d_in[24];
    const float* fc2w   = (const float*)d_in[25];
    const float* fc2b   = (const float*)d_in[26];

    const int N = NPIX;                       // 12544
    const size_t NP = (size_t)N * CC;
    float* F0 = (float*)d_ws;                 // xn -> blended -> xn2
    float* F1 = F0 + NP;                      // xp -> x2
    float* F2 = F1 + NP;                      // off -> d -> h2
    float* F3 = F2 + NP;                      // x1
    float* Fm = F3 + NP;                      // mask logits N*96

    const int lnG = N / 4;     // 3136
    const int gmG = N / 32;    // 392

    // 1. xn = LN(x, norm1)                         -> F0
    ln4_k<<<lnG, 256, 0, stream>>>(x, n1w, n1b, F0, 1e-5f);
    // 2. xp = xn @ in_proj + b                     -> F1
    gemm_k<<<gmG, 256, 0, stream>>>(F0, inpw, inpb, F1, CC);
    // 3. x1 = gelu(LN(dwconv(xn), 1e-6))           -> F3
    dwconv_ln_gelu_k<<<N, 192, 0, stream>>>(F0, dww, dwb, dwlnw, dwlnb, F3);
    // 4. off = x1 @ off_w + b                      -> F2
    gemm_k<<<gmG, 256, 0, stream>>>(F3, offw, offb, F2, CC);
    // 5. mask logits = x1 @ mask_w + b             -> Fm
    gemm_k<<<gmG, 256, 0, stream>>>(F3, maskw, maskb, Fm, 96);
    // 6. blended = sample(xp, off, softmax(mlog), cfs(x1))   -> F0
    sample_k<<<N, 192, 0, stream>>>(F1, F3, F2, Fm, cfsw, cfsb, F0);
    // 7. d = blended @ out_proj + b                -> F2
    gemm_k<<<gmG, 256, 0, stream>>>(F0, outpw, outpb, F2, CC);
    // 8. x2 = x + LN(d, rpn1)                      -> F1
    add_ln4_k<<<lnG, 256, 0, stream>>>(x, F2, rpn1w, rpn1b, F1, 1e-5f);
    // 9. xn2 = LN(x2, norm2)                       -> F0
    ln4_k<<<lnG, 256, 0, stream>>>(F1, n2w, n2b, F0, 1e-5f);
    // 10. h2 = gelu(xn2 @ fc1 + b) @ fc2 + b       -> F2
    mlp_k<<<N / MT, 256, 0, stream>>>(F0, fc1w, fc1b, fc2w, fc2b, F2);
    // 11. out(fp32) = x2 + LN(h2, rpn2)            -> d_out
    add_ln4_k<<<lnG, 256, 0, stream>>>(F1, F2, rpn2w, rpn2b, (float*)d_out, 1e-5f);
}